// Round 7
// baseline (433.806 us; speedup 1.0000x reference)
//
#include <hip/hip_runtime.h>
#include <hip/hip_bf16.h>
#include <cstdint>

// ---------------------------------------------------------------------------
// RoPE Multi-Head Self-Attention, MI355X (gfx950)
// B=32, S=577, E=768, H=12, Dh=64.  Inputs fp32, output fp32 (r6-verified).
// Internally bf16 MFMA / fp32 accumulate; qkv workspace bf16.
// Round 14:
//  r13 POST-MORTEM: counted-vmcnt triple-buffer REGRESSED K1 103.4->110.7
//  (guide regime-gate confirmed: T4 needs the 8-phase schedule; null/negative
//  on 2-barrier 128^2).  Reverted to the r12 2-phase double-buffer.
//  NEW r14: C1/C2 eliminated.  K1 now converts fp32->bf16 IN its staging:
//  template gains independent AF32/BF32 flags; the f32 register-convert
//  staging (load pre-MFMA, cvt+ds_write post-MFMA) was already proven on
//  K4's B path.  K1 = <A=f32 x, B=f32 w_qkv> directly from inputs; removes
//  two dispatches + an 85 MB HBM round-trip.  x is L3-resident so A re-reads
//  across N-tiles stay cached.
//  [K1] qkv = bf16(x) @ bf16(w_qkv)^T   (both operands f32 reg-convert)
//  [K2] RoPE in-place on q,k patch rows
//  [K3] flash attention (r10 async K/V prefetch + swapped QK^T softmax)
//  [K4] out = O @ bf16(w_proj)^T  (A bf16 DMA, B f32 reg-convert, C f32)
// ---------------------------------------------------------------------------

typedef __attribute__((ext_vector_type(8))) short bf16x8;  // 8 bf16 = 4 VGPRs
typedef __attribute__((ext_vector_type(4))) float f32x4;

#define MFMA16(a, b, c) __builtin_amdgcn_mfma_f32_16x16x32_bf16((a), (b), (c), 0, 0, 0)

#define S_LEN 577
#define NHEAD 12
#define DHEAD 64
#define EMB   768
#define F3    2304   // 3*EMB
#define NT_KV 10     // ceil(577/64)
#define BUFO  (128 * 32)   // gemm LDS buffer stride (elements, 8 KiB)

// async global->LDS, 16B/lane; LDS dest must be wave-uniform base + lane*16.
__device__ __forceinline__ void gload_lds16(const __hip_bfloat16* g, __hip_bfloat16* l) {
    __builtin_amdgcn_global_load_lds(
        (const __attribute__((address_space(1))) unsigned int*)g,
        (__attribute__((address_space(3))) unsigned int*)l, 16, 0, 0);
}

// pack 2 float4 -> 8 bf16 in a uint4 (16B)
__device__ __forceinline__ uint4 cvt8_f32(float4 a, float4 b) {
    union { uint4 u; __hip_bfloat16 h[8]; } r;
    r.h[0] = __float2bfloat16(a.x); r.h[1] = __float2bfloat16(a.y);
    r.h[2] = __float2bfloat16(a.z); r.h[3] = __float2bfloat16(a.w);
    r.h[4] = __float2bfloat16(b.x); r.h[5] = __float2bfloat16(b.y);
    r.h[6] = __float2bfloat16(b.z); r.h[7] = __float2bfloat16(b.w);
    return r.u;
}

// ---------------------------------------------------------------------------
// K1/K4: C[m][n] = sum_k A[m][k] * B[n][k]
// A: AF32 ? fp32 register-convert staging : bf16 global_load_lds DMA.
// B: BF32 ? fp32 register-convert staging : bf16 DMA.  Row strides lda/ldb
//    in elements of the respective dtype.
// C: CF32 ? fp32 : bf16.  N%128==0, K%64==0; M guarded.
// 128x128 tile, BK=32, 16x16x32 MFMA, 4 waves x 4x4 acc frags.
// r11 chunk-XOR swizzle: LDS slot s of row r holds global chunk s^((r>>1)&3)
// (staging pre-swizzles the GLOBAL source; reads use quad^((lane15>>1)&3)).
// r12 2-phase double buffer (one barrier/K-step): f32 loads issue pre-MFMA,
// cvt+ds_write post-MFMA; DMA gloads stage direct.  Barrier drains all.
// ---------------------------------------------------------------------------
template<bool AF32, bool BF32, bool CF32>
__global__ __launch_bounds__(256) void gemm_a_dma(
    const void* __restrict__ Av, int lda,
    const void* __restrict__ Bv, int ldb,
    void* __restrict__ Cv, int M, int N, int K)
{
    __shared__ __hip_bfloat16 As[2 * BUFO];   // [buf][row][k-swz], 64B rows
    __shared__ __hip_bfloat16 Bs[2 * BUFO];

    const int t      = threadIdx.x;
    const int l      = t & 63;
    const int w      = t >> 6;
    const int lane15 = l & 15;
    const int quad   = l >> 4;

    const int n0 = blockIdx.x * 128;
    const int m0 = blockIdx.y * 128;
    const int wm = (w >> 1) * 64;
    const int wn = (w & 1) * 64;

    const int srow   = t >> 2;   // 0..63
    const int schunk = t & 3;    // 0..3 (16B chunks)
    const int fsw    = (t >> 3) & 3;
    const int gchunk = schunk ^ fsw;          // swizzled global chunk

    int ar0 = m0 + srow;       if (ar0 > M - 1) ar0 = M - 1;
    int ar1 = m0 + 64 + srow;  if (ar1 > M - 1) ar1 = M - 1;
    const int br0 = n0 + srow;
    const int br1 = n0 + 64 + srow;

    const size_t a0off = (size_t)ar0 * lda + gchunk * 8;
    const size_t a1off = (size_t)ar1 * lda + gchunk * 8;
    const size_t b0off = (size_t)br0 * ldb + gchunk * 8;
    const size_t b1off = (size_t)br1 * ldb + gchunk * 8;

    __hip_bfloat16* lAs0 = As + srow * 32 + schunk * 8;          // buf0 slots
    __hip_bfloat16* lAs1 = As + (64 + srow) * 32 + schunk * 8;
    __hip_bfloat16* lBs0 = Bs + srow * 32 + schunk * 8;
    __hip_bfloat16* lBs1 = Bs + (64 + srow) * 32 + schunk * 8;

    // read-side swizzle: ((row>>1)&3) == ((lane15>>1)&3) for all frag rows
    const int rsw = (quad ^ ((lane15 >> 1) & 3)) * 8;

    f32x4 acc[4][4] = {};

    // ---- prologue: stage K-step 0 into buffer 0 ----
    if constexpr (AF32) {
        const float* qa0 = (const float*)Av + a0off;
        const float* qa1 = (const float*)Av + a1off;
        *(uint4*)lAs0 = cvt8_f32(*(const float4*)qa0, *(const float4*)(qa0 + 4));
        *(uint4*)lAs1 = cvt8_f32(*(const float4*)qa1, *(const float4*)(qa1 + 4));
    } else {
        gload_lds16((const __hip_bfloat16*)Av + a0off, lAs0);
        gload_lds16((const __hip_bfloat16*)Av + a1off, lAs1);
    }
    if constexpr (BF32) {
        const float* pb0 = (const float*)Bv + b0off;
        const float* pb1 = (const float*)Bv + b1off;
        *(uint4*)lBs0 = cvt8_f32(*(const float4*)pb0, *(const float4*)(pb0 + 4));
        *(uint4*)lBs1 = cvt8_f32(*(const float4*)pb1, *(const float4*)(pb1 + 4));
    } else {
        gload_lds16((const __hip_bfloat16*)Bv + b0off, lBs0);
        gload_lds16((const __hip_bfloat16*)Bv + b1off, lBs1);
    }
    __syncthreads();

    // One 2-phase step: compute buffer CO while staging kn into buffer NO.
#define GEMM_STEP(kn, CO, NO)                                                 \
    {                                                                         \
        const bool has_next = (kn) < K;                                       \
        float4 a0 = {}, a1 = {}, a2 = {}, a3 = {};                            \
        float4 g0 = {}, g1 = {}, g2 = {}, g3 = {};                            \
        if (has_next) {                                                       \
            if constexpr (AF32) {                                             \
                const float* qa0 = (const float*)Av + a0off + (kn);           \
                const float* qa1 = (const float*)Av + a1off + (kn);           \
                a0 = *(const float4*)qa0; a1 = *(const float4*)(qa0 + 4);     \
                a2 = *(const float4*)qa1; a3 = *(const float4*)(qa1 + 4);     \
            } else {                                                          \
                gload_lds16((const __hip_bfloat16*)Av + a0off + (kn), lAs0 + (NO)); \
                gload_lds16((const __hip_bfloat16*)Av + a1off + (kn), lAs1 + (NO)); \
            }                                                                 \
            if constexpr (BF32) {                                             \
                const float* pb0 = (const float*)Bv + b0off + (kn);           \
                const float* pb1 = (const float*)Bv + b1off + (kn);           \
                g0 = *(const float4*)pb0; g1 = *(const float4*)(pb0 + 4);     \
                g2 = *(const float4*)pb1; g3 = *(const float4*)(pb1 + 4);     \
            } else {                                                          \
                gload_lds16((const __hip_bfloat16*)Bv + b0off + (kn), lBs0 + (NO)); \
                gload_lds16((const __hip_bfloat16*)Bv + b1off + (kn), lBs1 + (NO)); \
            }                                                                 \
        }                                                                     \
        bf16x8 a[4], b[4];                                                    \
        _Pragma("unroll")                                                     \
        for (int i = 0; i < 4; ++i)                                           \
            a[i] = *(const bf16x8*)(As + (CO) + (wm + i * 16 + lane15) * 32 + rsw); \
        _Pragma("unroll")                                                     \
        for (int j = 0; j < 4; ++j)                                           \
            b[j] = *(const bf16x8*)(Bs + (CO) + (wn + j * 16 + lane15) * 32 + rsw); \
        _Pragma("unroll")                                                     \
        for (int i = 0; i < 4; ++i)                                           \
            _Pragma("unroll")                                                 \
            for (int j = 0; j < 4; ++j)                                       \
                acc[i][j] = MFMA16(a[i], b[j], acc[i][j]);                    \
        if (has_next) {                                                       \
            if constexpr (AF32) {                                             \
                *(uint4*)(lAs0 + (NO)) = cvt8_f32(a0, a1);                    \
                *(uint4*)(lAs1 + (NO)) = cvt8_f32(a2, a3);                    \
            }                                                                 \
            if constexpr (BF32) {                                             \
                *(uint4*)(lBs0 + (NO)) = cvt8_f32(g0, g1);                    \
                *(uint4*)(lBs1 + (NO)) = cvt8_f32(g2, g3);                    \
            }                                                                 \
        }                                                                     \
        __syncthreads();                                                      \
    }

    for (int k0 = 0; k0 < K; k0 += 64) {
        GEMM_STEP(k0 + 32, 0,    BUFO)     // compute buf0, stage buf1
        GEMM_STEP(k0 + 64, BUFO, 0)        // compute buf1, stage buf0
    }
#undef GEMM_STEP

    // epilogue: C/D layout col=lane&15, row=quad*4+reg
    #pragma unroll
    for (int i = 0; i < 4; ++i) {
        #pragma unroll
        for (int r = 0; r < 4; ++r) {
            const int m = m0 + wm + i * 16 + quad * 4 + r;
            if (m < M) {
                #pragma unroll
                for (int j = 0; j < 4; ++j) {
                    const int n = n0 + wn + j * 16 + lane15;
                    if constexpr (CF32)
                        ((float*)Cv)[(size_t)m * N + n] = acc[i][j][r];
                    else
                        ((__hip_bfloat16*)Cv)[(size_t)m * N + n] = __float2bfloat16(acc[i][j][r]);
                }
            }
        }
    }
}

// ---------------------------------------------------------------------------
// K2: RoPE in-place on q and k for patch tokens (s >= 1) — r6-verified.
// ---------------------------------------------------------------------------
__global__ __launch_bounds__(256) void rope_kernel(__hip_bfloat16* __restrict__ qkv)
{
    const int p = blockIdx.x;    // 0..575 patch index
    const int b = blockIdx.y;
    const int l = threadIdx.x & 63;
    const int w = threadIdx.x >> 6;

    const int jj   = l & 31;
    const float i2 = (float)((jj >> 1) * 2);
    const float dv = __expf(-i2 * 0.28782313662425576f);   // ln(10000)/32
    const float inv = 1.0f / (23.0f + 1e-8f);
    const float cx = (float)(p % 24) * inv;
    const float cy = (float)(p / 24) * inv;
    const float ang = ((l < 32) ? cx : cy) * dv;
    const float c = __cosf(ang);
    const float s = __sinf(ang);
    const int nb = (l & 32) | ((jj + 31) & 31);   // lane of (j-1)%32, same half

    const size_t rowbase = ((size_t)(b * S_LEN + 1 + p)) * F3;

    for (int pr = w; pr < 24; pr += 4) {
        const int part = pr / 12;    // 0=q, 1=k
        const int h    = pr % 12;
        const size_t off = rowbase + (size_t)part * EMB + h * DHEAD + l;
        float v  = __bfloat162float(qkv[off]);
        float vp = __shfl(v, nb, 64);
        qkv[off] = __float2bfloat16(v * c + vp * s);
    }
}

// ---------------------------------------------------------------------------
// K3: MFMA flash attention, 512 threads (8 waves), Q tile = 128 rows.
// grid (qt=5, h=12, b=32). Wave w owns q rows w*16..w*16+15 of the tile.
// Q pre-scaled by 0.125. O written with row stride ldo (aliased onto qkv's
// q-region; each block overwrites exactly the q-cells only it reads).
//
// Ps aliased onto the Qs LDS region (Qs dead after frag load): LDS 36864 B
// -> 4 blocks/CU.  P write rows are wave-private (w*16+lane15), so the P
// round-trip needs only a same-wave lgkmcnt drain.
//
// r10a T14 async-STAGE: tile t+1's K/V global loads issue before barrier B;
// barrier B is raw s_barrier + lgkmcnt(0) only (NO vmcnt drain) so the loads
// stay in flight across the compute phase.  Barrier A (__syncthreads) drains
// vmcnt right where the data is consumed (LDS staging writes).
//
// r10b swapped QK^T: sf = mfma(Kfrag, Qfrag) gives S^T[key][q]; lane owns
// q=lane15's 64 keys (16 regs + quad-folds at xor16/xor32).  Scalar m/l.
// alpha/l broadcast to O-layout rows (q=quad*4+r) via 4 lane-reads.
// ---------------------------------------------------------------------------
__global__ __launch_bounds__(512) void attn_kernel(
    const __hip_bfloat16* __restrict__ qkv,
    __hip_bfloat16* __restrict__ attn_out, int ldo)
{
    __shared__ __hip_bfloat16 Qs[128][72];     // Q frags, then aliased as Ps
    __shared__ __hip_bfloat16 Ks[64][72];
    __shared__ __hip_bfloat16 Vt[64][72];      // transposed: Vt[d][s]

    const int t      = threadIdx.x;
    const int l      = t & 63;
    const int w      = t >> 6;     // 0..7
    const int lane15 = l & 15;
    const int quad   = l >> 4;

    const int q0 = blockIdx.x * 128;
    const int h  = blockIdx.y;
    const int b  = blockIdx.z;

    // staging index split (fixed per thread)
    const int krow = t >> 3, kseg = t & 7;   // K: row 0..63, 16B chunk 0..7
    const int vs   = t & 63, vdg = t >> 6;   // V: s 0..63, dim-group 0..7

    // ---- issue tile-0 K/V prefetch ----
    uint4 ku, vu;
    {
        int gk = krow; if (gk > S_LEN - 1) gk = S_LEN - 1;
        ku = ((const uint4*)(qkv + (size_t)(b * S_LEN + gk) * F3 + EMB + h * DHEAD))[kseg];
        int gv = vs;  if (gv > S_LEN - 1) gv = S_LEN - 1;
        vu = ((const uint4*)(qkv + (size_t)(b * S_LEN + gv) * F3 + 2 * EMB + h * DHEAD))[vdg];
    }

    // ---- stage Q (scaled): row = t>>2 (0..127), seg = t&3 (16 elems) ----
    {
        const int row = t >> 2, seg = t & 3;
        int gq = q0 + row; if (gq > S_LEN - 1) gq = S_LEN - 1;
        const uint4* src = (const uint4*)(qkv + (size_t)(b * S_LEN + gq) * F3 + h * DHEAD + seg * 16);
        uint4 u0 = src[0], u1 = src[1];
        const __hip_bfloat16* e0 = (const __hip_bfloat16*)&u0;
        const __hip_bfloat16* e1 = (const __hip_bfloat16*)&u1;
        #pragma unroll
        for (int i = 0; i < 8; ++i) {
            Qs[row][seg * 16 + i]     = __float2bfloat16(__bfloat162float(e0[i]) * 0.125f);
            Qs[row][seg * 16 + 8 + i] = __float2bfloat16(__bfloat162float(e1[i]) * 0.125f);
        }
    }
    __syncthreads();

    // B-operand frags for Q: B[n=lane&15 (q row)][k=quad*8+j]  (held whole loop)
    bf16x8 qf0 = *(const bf16x8*)&Qs[w * 16 + lane15][quad * 8];
    bf16x8 qf1 = *(const bf16x8*)&Qs[w * 16 + lane15][32 + quad * 8];

    f32x4 o[4] = {};                       // O[q=quad*4+r][d=ci*16+lane15]
    float m_i = -3.0e38f;                  // softmax state for q = lane15 (scalar)
    float l_i = 0.f;

    for (int ti = 0; ti < NT_KV; ++ti) {
        __syncthreads();   // A: prior tile's LDS reads done; vmcnt drain = consume prefetch
        // ---- write prefetched K tile: Ks[krow][kseg*8..] ----
        *(uint4*)&Ks[krow][kseg * 8] = ku;
        // ---- write prefetched V tile transposed ----
        {
            const __hip_bfloat16* e0 = (const __hip_bfloat16*)&vu;
            #pragma unroll
            for (int i = 0; i < 8; ++i)
                Vt[vdg * 8 + i][vs] = e0[i];
        }
        // ---- issue NEXT tile's K/V prefetch (stays in flight across B) ----
        if (ti + 1 < NT_KV) {
            int gk = (ti + 1) * 64 + krow; if (gk > S_LEN - 1) gk = S_LEN - 1;
            ku = ((const uint4*)(qkv + (size_t)(b * S_LEN + gk) * F3 + EMB + h * DHEAD))[kseg];
            int gv = (ti + 1) * 64 + vs;  if (gv > S_LEN - 1) gv = S_LEN - 1;
            vu = ((const uint4*)(qkv + (size_t)(b * S_LEN + gv) * F3 + 2 * EMB + h * DHEAD))[vdg];
        }
        // B: LDS writes visible; do NOT drain vmcnt (prefetch in flight)
        asm volatile("s_waitcnt lgkmcnt(0)" ::: "memory");
        __builtin_amdgcn_s_barrier();
        asm volatile("" ::: "memory");

        // ---- S^T = K Q^T: sf[nt][r] = S[key=nt*16+quad*4+r][q=lane15] ----
        f32x4 sf[4];
        #pragma unroll
        for (int nt = 0; nt < 4; ++nt) {
            f32x4 z = {0.f, 0.f, 0.f, 0.f};
            bf16x8 k0f = *(const bf16x8*)&Ks[nt * 16 + lane15][quad * 8];
            bf16x8 k1f = *(const bf16x8*)&Ks[nt * 16 + lane15][32 + quad * 8];
            z = MFMA16(k0f, qf0, z);
            z = MFMA16(k1f, qf1, z);
            sf[nt] = z;
        }
        const int s0 = ti * 64;
        #pragma unroll
        for (int nt = 0; nt < 4; ++nt)
            #pragma unroll
            for (int r = 0; r < 4; ++r)
                if (s0 + nt * 16 + quad * 4 + r >= S_LEN) sf[nt][r] = -1e30f;

        // ---- row max for q=lane15: 16 local + fold across quads ----
        float mx = fmaxf(fmaxf(sf[0][0], sf[0][1]), fmaxf(sf[0][2], sf[0][3]));
        #pragma unroll
        for (int nt = 1; nt < 4; ++nt)
            mx = fmaxf(mx, fmaxf(fmaxf(sf[nt][0], sf[nt][1]), fmaxf(sf[nt][2], sf[nt][3])));
        mx = fmaxf(mx, __shfl_xor(mx, 16, 64));
        mx = fmaxf(mx, __shfl_xor(mx, 32, 64));

        const float mnew  = fmaxf(m_i, mx);
        const float alpha = __expf(m_i - mnew);
        m_i = mnew;

        // ---- P = exp(S - m), row sum ----
        float sum = 0.f;
        #pragma unroll
        for (int nt = 0; nt < 4; ++nt) {
            #pragma unroll
            for (int r = 0; r < 4; ++r) {
                sf[nt][r] = __expf(sf[nt][r] - mnew);
                sum += sf[nt][r];
            }
        }
        sum += __shfl_xor(sum, 16, 64);
        sum += __shfl_xor(sum, 32, 64);
        l_i = l_i * alpha + sum;

        // ---- broadcast alpha to O-layout rows (q = quad*4+r lives in lane quad*4+r) ----
        float af[4];
        #pragma unroll
        for (int r = 0; r < 4; ++r)
            af[r] = __shfl(alpha, quad * 4 + r, 64);
        #pragma unroll
        for (int ci = 0; ci < 4; ++ci)
            #pragma unroll
            for (int r = 0; r < 4; ++r)
                o[ci][r] *= af[r];

        // ---- P: S^T lane layout -> LDS [q][key] (wave-private rows) ----
        #pragma unroll
        for (int nt = 0; nt < 4; ++nt)
            #pragma unroll
            for (int r = 0; r < 4; ++r)
                Qs[w * 16 + lane15][nt * 16 + quad * 4 + r] = __float2bfloat16(sf[nt][r]);
        asm volatile("s_waitcnt lgkmcnt(0)" ::: "memory");

        // ---- O += P V ----
        #pragma unroll
        for (int s32 = 0; s32 < 2; ++s32) {
            bf16x8 pa = *(const bf16x8*)&Qs[w * 16 + lane15][s32 * 32 + quad * 8];
            #pragma unroll
            for (int ci = 0; ci < 4; ++ci) {
                bf16x8 vb = *(const bf16x8*)&Vt[ci * 16 + lane15][s32 * 32 + quad * 8];
                o[ci] = MFMA16(pa, vb, o[ci]);
            }
        }
    }

    // ---- epilogue: O / l -> attn_out; l for row q=quad*4+r from lane quad*4+r ----
    #pragma unroll
    for (int r = 0; r < 4; ++r) {
        const float lr = __shfl(l_i, quad * 4 + r, 64);
        const int q = q0 + w * 16 + quad * 4 + r;
        if (q < S_LEN) {
            const float rl = 1.0f / lr;
            #pragma unroll
            for (int ci = 0; ci < 4; ++ci) {
                attn_out[(size_t)(b * S_LEN + q) * ldo + h * DHEAD + ci * 16 + lane15] =
                    __float2bfloat16(o[ci][r] * rl);
            }
        }
    }
}

// ---------------------------------------------------------------------------
extern "C" void kernel_launch(void* const* d_in, const int* in_sizes, int n_in,
                              void* d_out, int out_size, void* d_ws, size_t ws_size,
                              hipStream_t stream) {
    const float* x      = (const float*)d_in[0];
    const float* w_qkv  = (const float*)d_in[1];
    const float* w_proj = (const float*)d_in[2];
    for (int i = 0; i < n_in; ++i) {
        if      (in_sizes[i] == 32 * S_LEN * EMB) x      = (const float*)d_in[i];
        else if (in_sizes[i] == F3 * EMB)         w_qkv  = (const float*)d_in[i];
        else if (in_sizes[i] == EMB * EMB)        w_proj = (const float*)d_in[i];
    }
    float* out = (float*)d_out;     // fp32 output (r6-verified)

    const int Mrows = 32 * S_LEN;           // 18464

    __hip_bfloat16* qkv = (__hip_bfloat16*)d_ws;        // [M][2304] bf16, 81.1 MiB

    // K1: qkv = bf16(x) @ bf16(w_qkv)^T  (both f32 register-convert staging)
    gemm_a_dma<true, true, false><<<dim3(F3 / 128, (Mrows + 127) / 128), 256, 0, stream>>>(
        x, EMB, w_qkv, EMB, qkv, Mrows, F3, EMB);
    // K2: RoPE on q,k patch rows
    rope_kernel<<<dim3(576, 32), 256, 0, stream>>>(qkv);
    // K3: attention (512 thr, 128-row Q tiles); O overwrites q-region of qkv
    attn_kernel<<<dim3((S_LEN + 127) / 128, NHEAD, 32), 512, 0, stream>>>(qkv, qkv, F3);
    // K4: out = O @ bf16(w_proj)^T  (A DMA bf16 stride F3; B f32 convert; C f32)
    gemm_a_dma<false, true, true><<<dim3(EMB / 128, (Mrows + 127) / 128), 256, 0, stream>>>(
        qkv, F3, w_proj, EMB, out, Mrows, EMB, EMB);
}

// Round 8
// 388.046 us; speedup vs baseline: 1.1179x; 1.1179x over previous
//
#include <hip/hip_runtime.h>
#include <hip/hip_bf16.h>
#include <cstdint>

// ---------------------------------------------------------------------------
// RoPE Multi-Head Self-Attention, MI355X (gfx950)
// B=32, S=577, E=768, H=12, Dh=64.  Inputs fp32, output fp32 (r6-verified).
// Internally bf16 MFMA / fp32 accumulate; qkv workspace bf16.
// Round 15:
//  r14 POST-MORTEM: fusing fp32->bf16 A-convert into K1 blew FETCH 139->320MB
//  (x fp32 re-read by 18 N-tile columns; L3 thrashed) -> K1 103->166us.
//  REVERTED to r12 config: C1/C2 pre-convert + pure-bf16 DMA K1.
//  NEW r15 (attn): T5 s_setprio(1) around QK^T / PV MFMA clusters (4 blk/CU,
//  independent phases = the regime where setprio pays, m191 +4-7%); T13
//  defer-max THR=8 (skip alpha rescale + 4 bpermute broadcasts + 16 O-muls
//  when __all(mx - m_i <= 8); wave-uniform branch; P <= e^8 safe in bf16).
//  [C1,C2] convert x, w_qkv -> bf16 into d_out-as-scratch (dead until K4)
//  [K1] qkv = xb @ wb^T           (bf16 DMA staging, r11 swizzle, r12 2-phase)
//  [K2] RoPE in-place on q,k patch rows
//  [K3] flash attention (r10 async K/V prefetch + swapped QK^T + r15 T5/T13)
//  [K4] out = O @ bf16(w_proj)^T  (A bf16 DMA, B f32 reg-convert, C f32)
// ---------------------------------------------------------------------------

typedef __attribute__((ext_vector_type(8))) short bf16x8;  // 8 bf16 = 4 VGPRs
typedef __attribute__((ext_vector_type(4))) float f32x4;

#define MFMA16(a, b, c) __builtin_amdgcn_mfma_f32_16x16x32_bf16((a), (b), (c), 0, 0, 0)

#define S_LEN 577
#define NHEAD 12
#define DHEAD 64
#define EMB   768
#define F3    2304   // 3*EMB
#define NT_KV 10     // ceil(577/64)
#define BUFO  (128 * 32)   // gemm LDS buffer stride (elements, 8 KiB)

// async global->LDS, 16B/lane; LDS dest must be wave-uniform base + lane*16.
__device__ __forceinline__ void gload_lds16(const __hip_bfloat16* g, __hip_bfloat16* l) {
    __builtin_amdgcn_global_load_lds(
        (const __attribute__((address_space(1))) unsigned int*)g,
        (__attribute__((address_space(3))) unsigned int*)l, 16, 0, 0);
}

// pack 2 float4 -> 8 bf16 in a uint4 (16B)
__device__ __forceinline__ uint4 cvt8_f32(float4 a, float4 b) {
    union { uint4 u; __hip_bfloat16 h[8]; } r;
    r.h[0] = __float2bfloat16(a.x); r.h[1] = __float2bfloat16(a.y);
    r.h[2] = __float2bfloat16(a.z); r.h[3] = __float2bfloat16(a.w);
    r.h[4] = __float2bfloat16(b.x); r.h[5] = __float2bfloat16(b.y);
    r.h[6] = __float2bfloat16(b.z); r.h[7] = __float2bfloat16(b.w);
    return r.u;
}

// load 8 consecutive fp32, convert to bf16 packed in a uint4 (16B)
__device__ __forceinline__ uint4 load8_f32(const float* p) {
    return cvt8_f32(*(const float4*)p, *(const float4*)(p + 4));
}

// ---------------------------------------------------------------------------
// C1/C2: fp32 -> bf16 bulk convert (n must be a multiple of 8; ours are)
// ---------------------------------------------------------------------------
__global__ __launch_bounds__(256) void cvt_f32_bf16(
    const float* __restrict__ src, __hip_bfloat16* __restrict__ dst, int n8)
{
    const int i = blockIdx.x * 256 + threadIdx.x;
    if (i < n8)
        *(uint4*)(dst + (size_t)i * 8) = load8_f32(src + (size_t)i * 8);
}

// ---------------------------------------------------------------------------
// K1/K4: C[m][n] = sum_k A[m][k] * B[n][k]
// A: AF32 ? fp32 register-convert staging : bf16 global_load_lds DMA.
//    (AF32 unused this round -- r14 showed fp32-A re-reads blow HBM fetch.)
// B: BF32 ? fp32 register-convert staging : bf16 DMA.  Strides in elements.
// C: CF32 ? fp32 : bf16.  N%128==0, K%64==0; M guarded.
// 128x128 tile, BK=32, 16x16x32 MFMA, 4 waves x 4x4 acc frags.
// r11 chunk-XOR swizzle: LDS slot s of row r holds global chunk s^((r>>1)&3)
// (staging pre-swizzles the GLOBAL source; reads use quad^((lane15>>1)&3)).
// r12 2-phase double buffer (one barrier/K-step): f32 loads issue pre-MFMA,
// cvt+ds_write post-MFMA; DMA gloads stage direct.  Barrier drains all.
// ---------------------------------------------------------------------------
template<bool AF32, bool BF32, bool CF32>
__global__ __launch_bounds__(256) void gemm_a_dma(
    const void* __restrict__ Av, int lda,
    const void* __restrict__ Bv, int ldb,
    void* __restrict__ Cv, int M, int N, int K)
{
    __shared__ __hip_bfloat16 As[2 * BUFO];   // [buf][row][k-swz], 64B rows
    __shared__ __hip_bfloat16 Bs[2 * BUFO];

    const int t      = threadIdx.x;
    const int l      = t & 63;
    const int w      = t >> 6;
    const int lane15 = l & 15;
    const int quad   = l >> 4;

    const int n0 = blockIdx.x * 128;
    const int m0 = blockIdx.y * 128;
    const int wm = (w >> 1) * 64;
    const int wn = (w & 1) * 64;

    const int srow   = t >> 2;   // 0..63
    const int schunk = t & 3;    // 0..3 (16B chunks)
    const int fsw    = (t >> 3) & 3;
    const int gchunk = schunk ^ fsw;          // swizzled global chunk

    int ar0 = m0 + srow;       if (ar0 > M - 1) ar0 = M - 1;
    int ar1 = m0 + 64 + srow;  if (ar1 > M - 1) ar1 = M - 1;
    const int br0 = n0 + srow;
    const int br1 = n0 + 64 + srow;

    const size_t a0off = (size_t)ar0 * lda + gchunk * 8;
    const size_t a1off = (size_t)ar1 * lda + gchunk * 8;
    const size_t b0off = (size_t)br0 * ldb + gchunk * 8;
    const size_t b1off = (size_t)br1 * ldb + gchunk * 8;

    __hip_bfloat16* lAs0 = As + srow * 32 + schunk * 8;          // buf0 slots
    __hip_bfloat16* lAs1 = As + (64 + srow) * 32 + schunk * 8;
    __hip_bfloat16* lBs0 = Bs + srow * 32 + schunk * 8;
    __hip_bfloat16* lBs1 = Bs + (64 + srow) * 32 + schunk * 8;

    // read-side swizzle: ((row>>1)&3) == ((lane15>>1)&3) for all frag rows
    const int rsw = (quad ^ ((lane15 >> 1) & 3)) * 8;

    f32x4 acc[4][4] = {};

    // ---- prologue: stage K-step 0 into buffer 0 ----
    if constexpr (AF32) {
        const float* qa0 = (const float*)Av + a0off;
        const float* qa1 = (const float*)Av + a1off;
        *(uint4*)lAs0 = cvt8_f32(*(const float4*)qa0, *(const float4*)(qa0 + 4));
        *(uint4*)lAs1 = cvt8_f32(*(const float4*)qa1, *(const float4*)(qa1 + 4));
    } else {
        gload_lds16((const __hip_bfloat16*)Av + a0off, lAs0);
        gload_lds16((const __hip_bfloat16*)Av + a1off, lAs1);
    }
    if constexpr (BF32) {
        const float* pb0 = (const float*)Bv + b0off;
        const float* pb1 = (const float*)Bv + b1off;
        *(uint4*)lBs0 = cvt8_f32(*(const float4*)pb0, *(const float4*)(pb0 + 4));
        *(uint4*)lBs1 = cvt8_f32(*(const float4*)pb1, *(const float4*)(pb1 + 4));
    } else {
        gload_lds16((const __hip_bfloat16*)Bv + b0off, lBs0);
        gload_lds16((const __hip_bfloat16*)Bv + b1off, lBs1);
    }
    __syncthreads();

    // One 2-phase step: compute buffer CO while staging kn into buffer NO.
#define GEMM_STEP(kn, CO, NO)                                                 \
    {                                                                         \
        const bool has_next = (kn) < K;                                       \
        float4 a0 = {}, a1 = {}, a2 = {}, a3 = {};                            \
        float4 g0 = {}, g1 = {}, g2 = {}, g3 = {};                            \
        if (has_next) {                                                       \
            if constexpr (AF32) {                                             \
                const float* qa0 = (const float*)Av + a0off + (kn);           \
                const float* qa1 = (const float*)Av + a1off + (kn);           \
                a0 = *(const float4*)qa0; a1 = *(const float4*)(qa0 + 4);     \
                a2 = *(const float4*)qa1; a3 = *(const float4*)(qa1 + 4);     \
            } else {                                                          \
                gload_lds16((const __hip_bfloat16*)Av + a0off + (kn), lAs0 + (NO)); \
                gload_lds16((const __hip_bfloat16*)Av + a1off + (kn), lAs1 + (NO)); \
            }                                                                 \
            if constexpr (BF32) {                                             \
                const float* pb0 = (const float*)Bv + b0off + (kn);           \
                const float* pb1 = (const float*)Bv + b1off + (kn);           \
                g0 = *(const float4*)pb0; g1 = *(const float4*)(pb0 + 4);     \
                g2 = *(const float4*)pb1; g3 = *(const float4*)(pb1 + 4);     \
            } else {                                                          \
                gload_lds16((const __hip_bfloat16*)Bv + b0off + (kn), lBs0 + (NO)); \
                gload_lds16((const __hip_bfloat16*)Bv + b1off + (kn), lBs1 + (NO)); \
            }                                                                 \
        }                                                                     \
        bf16x8 a[4], b[4];                                                    \
        _Pragma("unroll")                                                     \
        for (int i = 0; i < 4; ++i)                                           \
            a[i] = *(const bf16x8*)(As + (CO) + (wm + i * 16 + lane15) * 32 + rsw); \
        _Pragma("unroll")                                                     \
        for (int j = 0; j < 4; ++j)                                           \
            b[j] = *(const bf16x8*)(Bs + (CO) + (wn + j * 16 + lane15) * 32 + rsw); \
        _Pragma("unroll")                                                     \
        for (int i = 0; i < 4; ++i)                                           \
            _Pragma("unroll")                                                 \
            for (int j = 0; j < 4; ++j)                                       \
                acc[i][j] = MFMA16(a[i], b[j], acc[i][j]);                    \
        if (has_next) {                                                       \
            if constexpr (AF32) {                                             \
                *(uint4*)(lAs0 + (NO)) = cvt8_f32(a0, a1);                    \
                *(uint4*)(lAs1 + (NO)) = cvt8_f32(a2, a3);                    \
            }                                                                 \
            if constexpr (BF32) {                                             \
                *(uint4*)(lBs0 + (NO)) = cvt8_f32(g0, g1);                    \
                *(uint4*)(lBs1 + (NO)) = cvt8_f32(g2, g3);                    \
            }                                                                 \
        }                                                                     \
        __syncthreads();                                                      \
    }

    for (int k0 = 0; k0 < K; k0 += 64) {
        GEMM_STEP(k0 + 32, 0,    BUFO)     // compute buf0, stage buf1
        GEMM_STEP(k0 + 64, BUFO, 0)        // compute buf1, stage buf0
    }
#undef GEMM_STEP

    // epilogue: C/D layout col=lane&15, row=quad*4+reg
    #pragma unroll
    for (int i = 0; i < 4; ++i) {
        #pragma unroll
        for (int r = 0; r < 4; ++r) {
            const int m = m0 + wm + i * 16 + quad * 4 + r;
            if (m < M) {
                #pragma unroll
                for (int j = 0; j < 4; ++j) {
                    const int n = n0 + wn + j * 16 + lane15;
                    if constexpr (CF32)
                        ((float*)Cv)[(size_t)m * N + n] = acc[i][j][r];
                    else
                        ((__hip_bfloat16*)Cv)[(size_t)m * N + n] = __float2bfloat16(acc[i][j][r]);
                }
            }
        }
    }
}

// ---------------------------------------------------------------------------
// K2: RoPE in-place on q and k for patch tokens (s >= 1) — r6-verified.
// ---------------------------------------------------------------------------
__global__ __launch_bounds__(256) void rope_kernel(__hip_bfloat16* __restrict__ qkv)
{
    const int p = blockIdx.x;    // 0..575 patch index
    const int b = blockIdx.y;
    const int l = threadIdx.x & 63;
    const int w = threadIdx.x >> 6;

    const int jj   = l & 31;
    const float i2 = (float)((jj >> 1) * 2);
    const float dv = __expf(-i2 * 0.28782313662425576f);   // ln(10000)/32
    const float inv = 1.0f / (23.0f + 1e-8f);
    const float cx = (float)(p % 24) * inv;
    const float cy = (float)(p / 24) * inv;
    const float ang = ((l < 32) ? cx : cy) * dv;
    const float c = __cosf(ang);
    const float s = __sinf(ang);
    const int nb = (l & 32) | ((jj + 31) & 31);   // lane of (j-1)%32, same half

    const size_t rowbase = ((size_t)(b * S_LEN + 1 + p)) * F3;

    for (int pr = w; pr < 24; pr += 4) {
        const int part = pr / 12;    // 0=q, 1=k
        const int h    = pr % 12;
        const size_t off = rowbase + (size_t)part * EMB + h * DHEAD + l;
        float v  = __bfloat162float(qkv[off]);
        float vp = __shfl(v, nb, 64);
        qkv[off] = __float2bfloat16(v * c + vp * s);
    }
}

// ---------------------------------------------------------------------------
// K3: MFMA flash attention, 512 threads (8 waves), Q tile = 128 rows.
// grid (qt=5, h=12, b=32). Wave w owns q rows w*16..w*16+15 of the tile.
// Q pre-scaled by 0.125. O written with row stride ldo (aliased onto qkv's
// q-region; each block overwrites exactly the q-cells only it reads).
//
// Ps aliased onto the Qs LDS region (Qs dead after frag load): LDS 36864 B
// -> 4 blocks/CU.  P write rows are wave-private (w*16+lane15): same-wave
// lgkmcnt drain suffices.
// r10a async K/V prefetch (raw s_barrier, no vmcnt drain on barrier B).
// r10b swapped QK^T (S^T; lane owns q=lane15's 64 keys; scalar m/l).
// r15 T5: s_setprio(1) around MFMA clusters (4 blk/CU independent phases).
// r15 T13: defer-max THR=8 -- skip rescale (exp, 4 bpermute, 16 muls) when
// __all(mx - m_i <= 8); l_i *= alpha factored before the sum-add so both
// paths share the exp loop.  First tile always rescales (m_i = -3e38).
// ---------------------------------------------------------------------------
__global__ __launch_bounds__(512) void attn_kernel(
    const __hip_bfloat16* __restrict__ qkv,
    __hip_bfloat16* __restrict__ attn_out, int ldo)
{
    __shared__ __hip_bfloat16 Qs[128][72];     // Q frags, then aliased as Ps
    __shared__ __hip_bfloat16 Ks[64][72];
    __shared__ __hip_bfloat16 Vt[64][72];      // transposed: Vt[d][s]

    const int t      = threadIdx.x;
    const int l      = t & 63;
    const int w      = t >> 6;     // 0..7
    const int lane15 = l & 15;
    const int quad   = l >> 4;

    const int q0 = blockIdx.x * 128;
    const int h  = blockIdx.y;
    const int b  = blockIdx.z;

    // staging index split (fixed per thread)
    const int krow = t >> 3, kseg = t & 7;   // K: row 0..63, 16B chunk 0..7
    const int vs   = t & 63, vdg = t >> 6;   // V: s 0..63, dim-group 0..7

    // ---- issue tile-0 K/V prefetch ----
    uint4 ku, vu;
    {
        int gk = krow; if (gk > S_LEN - 1) gk = S_LEN - 1;
        ku = ((const uint4*)(qkv + (size_t)(b * S_LEN + gk) * F3 + EMB + h * DHEAD))[kseg];
        int gv = vs;  if (gv > S_LEN - 1) gv = S_LEN - 1;
        vu = ((const uint4*)(qkv + (size_t)(b * S_LEN + gv) * F3 + 2 * EMB + h * DHEAD))[vdg];
    }

    // ---- stage Q (scaled): row = t>>2 (0..127), seg = t&3 (16 elems) ----
    {
        const int row = t >> 2, seg = t & 3;
        int gq = q0 + row; if (gq > S_LEN - 1) gq = S_LEN - 1;
        const uint4* src = (const uint4*)(qkv + (size_t)(b * S_LEN + gq) * F3 + h * DHEAD + seg * 16);
        uint4 u0 = src[0], u1 = src[1];
        const __hip_bfloat16* e0 = (const __hip_bfloat16*)&u0;
        const __hip_bfloat16* e1 = (const __hip_bfloat16*)&u1;
        #pragma unroll
        for (int i = 0; i < 8; ++i) {
            Qs[row][seg * 16 + i]     = __float2bfloat16(__bfloat162float(e0[i]) * 0.125f);
            Qs[row][seg * 16 + 8 + i] = __float2bfloat16(__bfloat162float(e1[i]) * 0.125f);
        }
    }
    __syncthreads();

    // B-operand frags for Q: B[n=lane&15 (q row)][k=quad*8+j]  (held whole loop)
    bf16x8 qf0 = *(const bf16x8*)&Qs[w * 16 + lane15][quad * 8];
    bf16x8 qf1 = *(const bf16x8*)&Qs[w * 16 + lane15][32 + quad * 8];

    f32x4 o[4] = {};                       // O[q=quad*4+r][d=ci*16+lane15]
    float m_i = -3.0e38f;                  // softmax state for q = lane15 (scalar)
    float l_i = 0.f;

    for (int ti = 0; ti < NT_KV; ++ti) {
        __syncthreads();   // A: prior tile's LDS reads done; vmcnt drain = consume prefetch
        // ---- write prefetched K tile: Ks[krow][kseg*8..] ----
        *(uint4*)&Ks[krow][kseg * 8] = ku;
        // ---- write prefetched V tile transposed ----
        {
            const __hip_bfloat16* e0 = (const __hip_bfloat16*)&vu;
            #pragma unroll
            for (int i = 0; i < 8; ++i)
                Vt[vdg * 8 + i][vs] = e0[i];
        }
        // ---- issue NEXT tile's K/V prefetch (stays in flight across B) ----
        if (ti + 1 < NT_KV) {
            int gk = (ti + 1) * 64 + krow; if (gk > S_LEN - 1) gk = S_LEN - 1;
            ku = ((const uint4*)(qkv + (size_t)(b * S_LEN + gk) * F3 + EMB + h * DHEAD))[kseg];
            int gv = (ti + 1) * 64 + vs;  if (gv > S_LEN - 1) gv = S_LEN - 1;
            vu = ((const uint4*)(qkv + (size_t)(b * S_LEN + gv) * F3 + 2 * EMB + h * DHEAD))[vdg];
        }
        // B: LDS writes visible; do NOT drain vmcnt (prefetch in flight)
        asm volatile("s_waitcnt lgkmcnt(0)" ::: "memory");
        __builtin_amdgcn_s_barrier();
        asm volatile("" ::: "memory");

        // ---- S^T = K Q^T: sf[nt][r] = S[key=nt*16+quad*4+r][q=lane15] ----
        f32x4 sf[4];
        __builtin_amdgcn_s_setprio(1);
        #pragma unroll
        for (int nt = 0; nt < 4; ++nt) {
            f32x4 z = {0.f, 0.f, 0.f, 0.f};
            bf16x8 k0f = *(const bf16x8*)&Ks[nt * 16 + lane15][quad * 8];
            bf16x8 k1f = *(const bf16x8*)&Ks[nt * 16 + lane15][32 + quad * 8];
            z = MFMA16(k0f, qf0, z);
            z = MFMA16(k1f, qf1, z);
            sf[nt] = z;
        }
        __builtin_amdgcn_s_setprio(0);
        const int s0 = ti * 64;
        #pragma unroll
        for (int nt = 0; nt < 4; ++nt)
            #pragma unroll
            for (int r = 0; r < 4; ++r)
                if (s0 + nt * 16 + quad * 4 + r >= S_LEN) sf[nt][r] = -1e30f;

        // ---- row max for q=lane15: 16 local + fold across quads ----
        float mx = fmaxf(fmaxf(sf[0][0], sf[0][1]), fmaxf(sf[0][2], sf[0][3]));
        #pragma unroll
        for (int nt = 1; nt < 4; ++nt)
            mx = fmaxf(mx, fmaxf(fmaxf(sf[nt][0], sf[nt][1]), fmaxf(sf[nt][2], sf[nt][3])));
        mx = fmaxf(mx, __shfl_xor(mx, 16, 64));
        mx = fmaxf(mx, __shfl_xor(mx, 32, 64));

        // ---- T13 defer-max: only rescale when some row grew by > THR ----
        if (!__all(mx - m_i <= 8.0f)) {
            const float mnew  = fmaxf(m_i, mx);
            const float alpha = __expf(m_i - mnew);
            m_i = mnew;
            l_i *= alpha;
            float af[4];
            #pragma unroll
            for (int r = 0; r < 4; ++r)
                af[r] = __shfl(alpha, quad * 4 + r, 64);
            #pragma unroll
            for (int ci = 0; ci < 4; ++ci)
                #pragma unroll
                for (int r = 0; r < 4; ++r)
                    o[ci][r] *= af[r];
        }

        // ---- P = exp(S - m_i), row sum (shared by both paths) ----
        float sum = 0.f;
        #pragma unroll
        for (int nt = 0; nt < 4; ++nt) {
            #pragma unroll
            for (int r = 0; r < 4; ++r) {
                sf[nt][r] = __expf(sf[nt][r] - m_i);
                sum += sf[nt][r];
            }
        }
        sum += __shfl_xor(sum, 16, 64);
        sum += __shfl_xor(sum, 32, 64);
        l_i += sum;

        // ---- P: S^T lane layout -> LDS [q][key] (wave-private rows) ----
        #pragma unroll
        for (int nt = 0; nt < 4; ++nt)
            #pragma unroll
            for (int r = 0; r < 4; ++r)
                Qs[w * 16 + lane15][nt * 16 + quad * 4 + r] = __float2bfloat16(sf[nt][r]);
        asm volatile("s_waitcnt lgkmcnt(0)" ::: "memory");

        // ---- O += P V ----
        __builtin_amdgcn_s_setprio(1);
        #pragma unroll
        for (int s32 = 0; s32 < 2; ++s32) {
            bf16x8 pa = *(const bf16x8*)&Qs[w * 16 + lane15][s32 * 32 + quad * 8];
            #pragma unroll
            for (int ci = 0; ci < 4; ++ci) {
                bf16x8 vb = *(const bf16x8*)&Vt[ci * 16 + lane15][s32 * 32 + quad * 8];
                o[ci] = MFMA16(pa, vb, o[ci]);
            }
        }
        __builtin_amdgcn_s_setprio(0);
    }

    // ---- epilogue: O / l -> attn_out; l for row q=quad*4+r from lane quad*4+r ----
    #pragma unroll
    for (int r = 0; r < 4; ++r) {
        const float lr = __shfl(l_i, quad * 4 + r, 64);
        const int q = q0 + w * 16 + quad * 4 + r;
        if (q < S_LEN) {
            const float rl = 1.0f / lr;
            #pragma unroll
            for (int ci = 0; ci < 4; ++ci) {
                attn_out[(size_t)(b * S_LEN + q) * ldo + h * DHEAD + ci * 16 + lane15] =
                    __float2bfloat16(o[ci][r] * rl);
            }
        }
    }
}

// ---------------------------------------------------------------------------
extern "C" void kernel_launch(void* const* d_in, const int* in_sizes, int n_in,
                              void* d_out, int out_size, void* d_ws, size_t ws_size,
                              hipStream_t stream) {
    const float* x      = (const float*)d_in[0];
    const float* w_qkv  = (const float*)d_in[1];
    const float* w_proj = (const float*)d_in[2];
    for (int i = 0; i < n_in; ++i) {
        if      (in_sizes[i] == 32 * S_LEN * EMB) x      = (const float*)d_in[i];
        else if (in_sizes[i] == F3 * EMB)         w_qkv  = (const float*)d_in[i];
        else if (in_sizes[i] == EMB * EMB)        w_proj = (const float*)d_in[i];
    }
    float* out = (float*)d_out;     // fp32 output (r6-verified)

    const int Mrows = 32 * S_LEN;           // 18464
    const int NX    = Mrows * EMB;          // 14,180,352 (mult of 8)
    const int NWQ   = F3 * EMB;             // 1,769,472  (mult of 8)

    __hip_bfloat16* qkv = (__hip_bfloat16*)d_ws;        // [M][2304] bf16, 81.1 MiB
    // d_out as scratch until K4 overwrites it: xb (28.4 MB) + wb (3.4 MB) < 56.7 MB
    __hip_bfloat16* xb  = (__hip_bfloat16*)d_out;
    __hip_bfloat16* wb  = xb + (size_t)NX;

    // C1/C2: fp32 -> bf16 converts into d_out scratch
    cvt_f32_bf16<<<NX / 8 / 256, 256, 0, stream>>>(x, xb, NX / 8);
    cvt_f32_bf16<<<NWQ / 8 / 256, 256, 0, stream>>>(w_qkv, wb, NWQ / 8);
    // K1: qkv = xb @ wb^T  (pure-bf16 DMA staging, bf16 C)
    gemm_a_dma<false, false, false><<<dim3(F3 / 128, (Mrows + 127) / 128), 256, 0, stream>>>(
        xb, EMB, wb, EMB, qkv, Mrows, F3, EMB);
    // K2: RoPE on q,k patch rows
    rope_kernel<<<dim3(576, 32), 256, 0, stream>>>(qkv);
    // K3: attention (512 thr, 128-row Q tiles); O overwrites q-region of qkv
    attn_kernel<<<dim3((S_LEN + 127) / 128, NHEAD, 32), 512, 0, stream>>>(qkv, qkv, F3);
    // K4: out = O @ bf16(w_proj)^T  (A DMA bf16 stride F3; B f32 convert; C f32)
    gemm_a_dma<false, true, true><<<dim3(EMB / 128, (Mrows + 127) / 128), 256, 0, stream>>>(
        qkv, F3, w_proj, EMB, out, Mrows, EMB, EMB);
}

// Round 9
// 366.573 us; speedup vs baseline: 1.1834x; 1.0586x over previous
//
#include <hip/hip_runtime.h>
#include <hip/hip_bf16.h>
#include <cstdint>

// ---------------------------------------------------------------------------
// RoPE Multi-Head Self-Attention, MI355X (gfx950)
// B=32, S=577, E=768, H=12, Dh=64.  Inputs fp32, output fp32 (r6-verified).
// Internally bf16 MFMA / fp32 accumulate; qkv workspace bf16.
// Round 16:
//  NEW r16: dispatch-count surgery.  (a) RoPE fused into attn staging --
//  Q rope at Q-stage (once), K rope at K-tile write (per tile); one __shfl
//  per thread fetches the rotation neighbor (Q: lane^1 v[15]; K: lane+/-{1,3}
//  v[7]); cos/sin per PAIR (angles repeat 2x), K dv hoisted.  Kills the K2
//  kernel + its 113MB qkv round-trip + a launch gap.  (b) C1+C2 merged into
//  one dispatch (block-range split).  6 -> 4 dispatches.  GEMMs untouched.
//  [C] convert x, w_qkv -> bf16 into d_out-as-scratch (single dispatch)
//  [K1] qkv = xb @ wb^T           (bf16 DMA staging, r11 swizzle, r12 2-phase)
//  [K3] flash attention (r10 prefetch + swapped QK^T + r15 T5/T13 + r16 rope)
//  [K4] out = O @ bf16(w_proj)^T  (A bf16 DMA, B f32 reg-convert, C f32)
// ---------------------------------------------------------------------------

typedef __attribute__((ext_vector_type(8))) short bf16x8;  // 8 bf16 = 4 VGPRs
typedef __attribute__((ext_vector_type(4))) float f32x4;

#define MFMA16(a, b, c) __builtin_amdgcn_mfma_f32_16x16x32_bf16((a), (b), (c), 0, 0, 0)

#define S_LEN 577
#define NHEAD 12
#define DHEAD 64
#define EMB   768
#define F3    2304   // 3*EMB
#define NT_KV 10     // ceil(577/64)
#define BUFO  (128 * 32)   // gemm LDS buffer stride (elements, 8 KiB)
#define LN1E4_32 0.28782313662425576f   // ln(10000)/32

// async global->LDS, 16B/lane; LDS dest must be wave-uniform base + lane*16.
__device__ __forceinline__ void gload_lds16(const __hip_bfloat16* g, __hip_bfloat16* l) {
    __builtin_amdgcn_global_load_lds(
        (const __attribute__((address_space(1))) unsigned int*)g,
        (__attribute__((address_space(3))) unsigned int*)l, 16, 0, 0);
}

// pack 2 float4 -> 8 bf16 in a uint4 (16B)
__device__ __forceinline__ uint4 cvt8_f32(float4 a, float4 b) {
    union { uint4 u; __hip_bfloat16 h[8]; } r;
    r.h[0] = __float2bfloat16(a.x); r.h[1] = __float2bfloat16(a.y);
    r.h[2] = __float2bfloat16(a.z); r.h[3] = __float2bfloat16(a.w);
    r.h[4] = __float2bfloat16(b.x); r.h[5] = __float2bfloat16(b.y);
    r.h[6] = __float2bfloat16(b.z); r.h[7] = __float2bfloat16(b.w);
    return r.u;
}

// load 8 consecutive fp32, convert to bf16 packed in a uint4 (16B)
__device__ __forceinline__ uint4 load8_f32(const float* p) {
    return cvt8_f32(*(const float4*)p, *(const float4*)(p + 4));
}

// ---------------------------------------------------------------------------
// C: fp32 -> bf16 bulk convert, BOTH arrays in one dispatch.
// Blocks [0,xblocks) handle x (nx8 groups); the rest handle w (nw8 groups).
// ---------------------------------------------------------------------------
__global__ __launch_bounds__(256) void cvt_pair(
    const float* __restrict__ xs, __hip_bfloat16* __restrict__ xd, int nx8,
    const float* __restrict__ ws, __hip_bfloat16* __restrict__ wd, int nw8,
    int xblocks)
{
    if ((int)blockIdx.x < xblocks) {
        const int i = blockIdx.x * 256 + threadIdx.x;
        if (i < nx8)
            *(uint4*)(xd + (size_t)i * 8) = load8_f32(xs + (size_t)i * 8);
    } else {
        const int i = (blockIdx.x - xblocks) * 256 + threadIdx.x;
        if (i < nw8)
            *(uint4*)(wd + (size_t)i * 8) = load8_f32(ws + (size_t)i * 8);
    }
}

// ---------------------------------------------------------------------------
// K1/K4: C[m][n] = sum_k A[m][k] * B[n][k]
// A: AF32 ? fp32 register-convert staging : bf16 global_load_lds DMA.
//    (AF32 unused -- r14 showed fp32-A re-reads blow HBM fetch.)
// B: BF32 ? fp32 register-convert staging : bf16 DMA.  Strides in elements.
// C: CF32 ? fp32 : bf16.  N%128==0, K%64==0; M guarded.
// 128x128 tile, BK=32, 16x16x32 MFMA, 4 waves x 4x4 acc frags.
// r11 chunk-XOR swizzle: LDS slot s of row r holds global chunk s^((r>>1)&3)
// (staging pre-swizzles the GLOBAL source; reads use quad^((lane15>>1)&3)).
// r12 2-phase double buffer (one barrier/K-step): f32 loads issue pre-MFMA,
// cvt+ds_write post-MFMA; DMA gloads stage direct.  Barrier drains all.
// ---------------------------------------------------------------------------
template<bool AF32, bool BF32, bool CF32>
__global__ __launch_bounds__(256) void gemm_a_dma(
    const void* __restrict__ Av, int lda,
    const void* __restrict__ Bv, int ldb,
    void* __restrict__ Cv, int M, int N, int K)
{
    __shared__ __hip_bfloat16 As[2 * BUFO];   // [buf][row][k-swz], 64B rows
    __shared__ __hip_bfloat16 Bs[2 * BUFO];

    const int t      = threadIdx.x;
    const int l      = t & 63;
    const int w      = t >> 6;
    const int lane15 = l & 15;
    const int quad   = l >> 4;

    const int n0 = blockIdx.x * 128;
    const int m0 = blockIdx.y * 128;
    const int wm = (w >> 1) * 64;
    const int wn = (w & 1) * 64;

    const int srow   = t >> 2;   // 0..63
    const int schunk = t & 3;    // 0..3 (16B chunks)
    const int fsw    = (t >> 3) & 3;
    const int gchunk = schunk ^ fsw;          // swizzled global chunk

    int ar0 = m0 + srow;       if (ar0 > M - 1) ar0 = M - 1;
    int ar1 = m0 + 64 + srow;  if (ar1 > M - 1) ar1 = M - 1;
    const int br0 = n0 + srow;
    const int br1 = n0 + 64 + srow;

    const size_t a0off = (size_t)ar0 * lda + gchunk * 8;
    const size_t a1off = (size_t)ar1 * lda + gchunk * 8;
    const size_t b0off = (size_t)br0 * ldb + gchunk * 8;
    const size_t b1off = (size_t)br1 * ldb + gchunk * 8;

    __hip_bfloat16* lAs0 = As + srow * 32 + schunk * 8;          // buf0 slots
    __hip_bfloat16* lAs1 = As + (64 + srow) * 32 + schunk * 8;
    __hip_bfloat16* lBs0 = Bs + srow * 32 + schunk * 8;
    __hip_bfloat16* lBs1 = Bs + (64 + srow) * 32 + schunk * 8;

    // read-side swizzle: ((row>>1)&3) == ((lane15>>1)&3) for all frag rows
    const int rsw = (quad ^ ((lane15 >> 1) & 3)) * 8;

    f32x4 acc[4][4] = {};

    // ---- prologue: stage K-step 0 into buffer 0 ----
    if constexpr (AF32) {
        const float* qa0 = (const float*)Av + a0off;
        const float* qa1 = (const float*)Av + a1off;
        *(uint4*)lAs0 = cvt8_f32(*(const float4*)qa0, *(const float4*)(qa0 + 4));
        *(uint4*)lAs1 = cvt8_f32(*(const float4*)qa1, *(const float4*)(qa1 + 4));
    } else {
        gload_lds16((const __hip_bfloat16*)Av + a0off, lAs0);
        gload_lds16((const __hip_bfloat16*)Av + a1off, lAs1);
    }
    if constexpr (BF32) {
        const float* pb0 = (const float*)Bv + b0off;
        const float* pb1 = (const float*)Bv + b1off;
        *(uint4*)lBs0 = cvt8_f32(*(const float4*)pb0, *(const float4*)(pb0 + 4));
        *(uint4*)lBs1 = cvt8_f32(*(const float4*)pb1, *(const float4*)(pb1 + 4));
    } else {
        gload_lds16((const __hip_bfloat16*)Bv + b0off, lBs0);
        gload_lds16((const __hip_bfloat16*)Bv + b1off, lBs1);
    }
    __syncthreads();

    // One 2-phase step: compute buffer CO while staging kn into buffer NO.
#define GEMM_STEP(kn, CO, NO)                                                 \
    {                                                                         \
        const bool has_next = (kn) < K;                                       \
        float4 a0 = {}, a1 = {}, a2 = {}, a3 = {};                            \
        float4 g0 = {}, g1 = {}, g2 = {}, g3 = {};                            \
        if (has_next) {                                                       \
            if constexpr (AF32) {                                             \
                const float* qa0 = (const float*)Av + a0off + (kn);           \
                const float* qa1 = (const float*)Av + a1off + (kn);           \
                a0 = *(const float4*)qa0; a1 = *(const float4*)(qa0 + 4);     \
                a2 = *(const float4*)qa1; a3 = *(const float4*)(qa1 + 4);     \
            } else {                                                          \
                gload_lds16((const __hip_bfloat16*)Av + a0off + (kn), lAs0 + (NO)); \
                gload_lds16((const __hip_bfloat16*)Av + a1off + (kn), lAs1 + (NO)); \
            }                                                                 \
            if constexpr (BF32) {                                             \
                const float* pb0 = (const float*)Bv + b0off + (kn);           \
                const float* pb1 = (const float*)Bv + b1off + (kn);           \
                g0 = *(const float4*)pb0; g1 = *(const float4*)(pb0 + 4);     \
                g2 = *(const float4*)pb1; g3 = *(const float4*)(pb1 + 4);     \
            } else {                                                          \
                gload_lds16((const __hip_bfloat16*)Bv + b0off + (kn), lBs0 + (NO)); \
                gload_lds16((const __hip_bfloat16*)Bv + b1off + (kn), lBs1 + (NO)); \
            }                                                                 \
        }                                                                     \
        bf16x8 a[4], b[4];                                                    \
        _Pragma("unroll")                                                     \
        for (int i = 0; i < 4; ++i)                                           \
            a[i] = *(const bf16x8*)(As + (CO) + (wm + i * 16 + lane15) * 32 + rsw); \
        _Pragma("unroll")                                                     \
        for (int j = 0; j < 4; ++j)                                           \
            b[j] = *(const bf16x8*)(Bs + (CO) + (wn + j * 16 + lane15) * 32 + rsw); \
        _Pragma("unroll")                                                     \
        for (int i = 0; i < 4; ++i)                                           \
            _Pragma("unroll")                                                 \
            for (int j = 0; j < 4; ++j)                                       \
                acc[i][j] = MFMA16(a[i], b[j], acc[i][j]);                    \
        if (has_next) {                                                       \
            if constexpr (AF32) {                                             \
                *(uint4*)(lAs0 + (NO)) = cvt8_f32(a0, a1);                    \
                *(uint4*)(lAs1 + (NO)) = cvt8_f32(a2, a3);                    \
            }                                                                 \
            if constexpr (BF32) {                                             \
                *(uint4*)(lBs0 + (NO)) = cvt8_f32(g0, g1);                    \
                *(uint4*)(lBs1 + (NO)) = cvt8_f32(g2, g3);                    \
            }                                                                 \
        }                                                                     \
        __syncthreads();                                                      \
    }

    for (int k0 = 0; k0 < K; k0 += 64) {
        GEMM_STEP(k0 + 32, 0,    BUFO)     // compute buf0, stage buf1
        GEMM_STEP(k0 + 64, BUFO, 0)        // compute buf1, stage buf0
    }
#undef GEMM_STEP

    // epilogue: C/D layout col=lane&15, row=quad*4+reg
    #pragma unroll
    for (int i = 0; i < 4; ++i) {
        #pragma unroll
        for (int r = 0; r < 4; ++r) {
            const int m = m0 + wm + i * 16 + quad * 4 + r;
            if (m < M) {
                #pragma unroll
                for (int j = 0; j < 4; ++j) {
                    const int n = n0 + wn + j * 16 + lane15;
                    if constexpr (CF32)
                        ((float*)Cv)[(size_t)m * N + n] = acc[i][j][r];
                    else
                        ((__hip_bfloat16*)Cv)[(size_t)m * N + n] = __float2bfloat16(acc[i][j][r]);
                }
            }
        }
    }
}

// ---------------------------------------------------------------------------
// K3: MFMA flash attention, 512 threads (8 waves), Q tile = 128 rows.
// grid (qt=5, h=12, b=32). Wave w owns q rows w*16..w*16+15 of the tile.
// O written with row stride ldo (aliased onto qkv's q-region; each block
// overwrites exactly the q-cells only it reads).
//
// Ps aliased onto the Qs LDS region (Qs dead after frag load): LDS 36864 B
// -> 4 blocks/CU.  P write rows are wave-private: same-wave lgkmcnt drain.
// r10a async K/V prefetch (raw s_barrier, no vmcnt drain on barrier B).
// r10b swapped QK^T (S^T; lane owns q=lane15's 64 keys; scalar m/l).
// r15 T5 setprio around MFMA clusters; T13 defer-max THR=8.
// r16 RoPE fused into staging (replaces the K2 kernel):
//   out[j] = v[j]*cos(a_j) + v[(j-1) mod 32, same half]*sin(a_j),
//   a_j = coord(p, half) * exp(-2*(jj>>1)*ln(1e4)/32), p = row-1; row 0
//   (CLS) passes through (c=1,s=0).  Pairs (2m,2m+1) share angles.  The one
//   out-of-chunk neighbor comes via a single __shfl: Q chunks (16 elems,
//   seg 0..3) from lane^1's v[15]; K chunks (8 elems, kseg 0..7) from lane
//   +3 (kseg%4==0) or -1, their v[7].  Q additionally scaled by 0.125 in
//   the same f32 expression (one fewer bf16 rounding than the old K2 path).
// ---------------------------------------------------------------------------
__global__ __launch_bounds__(512) void attn_kernel(
    const __hip_bfloat16* __restrict__ qkv,
    __hip_bfloat16* __restrict__ attn_out, int ldo)
{
    __shared__ __hip_bfloat16 Qs[128][72];     // Q frags, then aliased as Ps
    __shared__ __hip_bfloat16 Ks[64][72];
    __shared__ __hip_bfloat16 Vt[64][72];      // transposed: Vt[d][s]

    const int t      = threadIdx.x;
    const int l      = t & 63;
    const int w      = t >> 6;     // 0..7
    const int lane15 = l & 15;
    const int quad   = l >> 4;

    const int q0 = blockIdx.x * 128;
    const int h  = blockIdx.y;
    const int b  = blockIdx.z;

    // staging index split (fixed per thread)
    const int krow = t >> 3, kseg = t & 7;   // K: row 0..63, 16B chunk 0..7
    const int vs   = t & 63, vdg = t >> 6;   // V: s 0..63, dim-group 0..7

    const float cinv = 1.0f / (23.0f + 1e-8f);
    // K-rope dv, per pair m: jj>>1 = (kseg&3)*4 + m  (constant across tiles)
    float dvk[4];
    #pragma unroll
    for (int m = 0; m < 4; ++m)
        dvk[m] = __expf(-(float)(2 * ((kseg & 3) * 4 + m)) * LN1E4_32);
    const int ksrc = ((kseg & 3) == 0) ? (l + 3) : (l - 1);   // rope neighbor lane

    // ---- issue tile-0 K/V prefetch ----
    uint4 ku, vu;
    {
        int gk = krow; if (gk > S_LEN - 1) gk = S_LEN - 1;
        ku = ((const uint4*)(qkv + (size_t)(b * S_LEN + gk) * F3 + EMB + h * DHEAD))[kseg];
        int gv = vs;  if (gv > S_LEN - 1) gv = S_LEN - 1;
        vu = ((const uint4*)(qkv + (size_t)(b * S_LEN + gv) * F3 + 2 * EMB + h * DHEAD))[vdg];
    }

    // ---- stage Q with fused RoPE + 0.125 scale: row = t>>2, seg = t&3 ----
    {
        const int row = t >> 2, seg = t & 3;
        int gq = q0 + row; if (gq > S_LEN - 1) gq = S_LEN - 1;
        const uint4* src4 = (const uint4*)(qkv + (size_t)(b * S_LEN + gq) * F3 + h * DHEAD + seg * 16);
        union { uint4 u[2]; __hip_bfloat16 hh[16]; } qi;
        qi.u[0] = src4[0]; qi.u[1] = src4[1];
        float v[16];
        #pragma unroll
        for (int i = 0; i < 16; ++i) v[i] = __bfloat162float(qi.hh[i]);
        // neighbor for the chunk's first pair: partner seg (l^1), their v[15]
        const float ext = __shfl(v[15], l ^ 1, 64);
        const bool no_rope = (gq == 0);
        const int p = no_rope ? 0 : gq - 1;
        const float coord = ((seg >= 2) ? (float)(p / 24) : (float)(p % 24)) * cinv;
        union { uint4 u[2]; __hip_bfloat16 hh[16]; } qo;
        #pragma unroll
        for (int m = 0; m < 8; ++m) {
            const float dv = __expf(-(float)(2 * ((seg & 1) * 8 + m)) * LN1E4_32);
            const float ang = coord * dv;
            const float c1 = no_rope ? 1.0f : __cosf(ang);
            const float s1 = no_rope ? 0.0f : __sinf(ang);
            const float pe = (m == 0) ? ext : v[2 * m - 1];
            qo.hh[2 * m]     = __float2bfloat16((v[2 * m]     * c1 + pe       * s1) * 0.125f);
            qo.hh[2 * m + 1] = __float2bfloat16((v[2 * m + 1] * c1 + v[2 * m] * s1) * 0.125f);
        }
        *(uint4*)&Qs[row][seg * 16]     = qo.u[0];
        *(uint4*)&Qs[row][seg * 16 + 8] = qo.u[1];
    }
    __syncthreads();

    // B-operand frags for Q: B[n=lane&15 (q row)][k=quad*8+j]  (held whole loop)
    bf16x8 qf0 = *(const bf16x8*)&Qs[w * 16 + lane15][quad * 8];
    bf16x8 qf1 = *(const bf16x8*)&Qs[w * 16 + lane15][32 + quad * 8];

    f32x4 o[4] = {};                       // O[q=quad*4+r][d=ci*16+lane15]
    float m_i = -3.0e38f;                  // softmax state for q = lane15 (scalar)
    float l_i = 0.f;

    for (int ti = 0; ti < NT_KV; ++ti) {
        __syncthreads();   // A: prior tile's LDS reads done; vmcnt drain = consume prefetch
        // ---- write prefetched K tile with fused RoPE ----
        {
            int gk = ti * 64 + krow; if (gk > S_LEN - 1) gk = S_LEN - 1;
            union { uint4 u; __hip_bfloat16 hh[8]; } ki;
            ki.u = ku;
            float v[8];
            #pragma unroll
            for (int i = 0; i < 8; ++i) v[i] = __bfloat162float(ki.hh[i]);
            const float ext = __shfl(v[7], ksrc, 64);
            const bool no_rope = (gk == 0);
            const int p = no_rope ? 0 : gk - 1;
            const float coord = ((kseg >= 4) ? (float)(p / 24) : (float)(p % 24)) * cinv;
            union { uint4 u; __hip_bfloat16 hh[8]; } ko;
            #pragma unroll
            for (int m = 0; m < 4; ++m) {
                const float ang = coord * dvk[m];
                const float c1 = no_rope ? 1.0f : __cosf(ang);
                const float s1 = no_rope ? 0.0f : __sinf(ang);
                const float pe = (m == 0) ? ext : v[2 * m - 1];
                ko.hh[2 * m]     = __float2bfloat16(v[2 * m]     * c1 + pe       * s1);
                ko.hh[2 * m + 1] = __float2bfloat16(v[2 * m + 1] * c1 + v[2 * m] * s1);
            }
            *(uint4*)&Ks[krow][kseg * 8] = ko.u;
        }
        // ---- write prefetched V tile transposed (no rope) ----
        {
            const __hip_bfloat16* e0 = (const __hip_bfloat16*)&vu;
            #pragma unroll
            for (int i = 0; i < 8; ++i)
                Vt[vdg * 8 + i][vs] = e0[i];
        }
        // ---- issue NEXT tile's K/V prefetch (stays in flight across B) ----
        if (ti + 1 < NT_KV) {
            int gk = (ti + 1) * 64 + krow; if (gk > S_LEN - 1) gk = S_LEN - 1;
            ku = ((const uint4*)(qkv + (size_t)(b * S_LEN + gk) * F3 + EMB + h * DHEAD))[kseg];
            int gv = (ti + 1) * 64 + vs;  if (gv > S_LEN - 1) gv = S_LEN - 1;
            vu = ((const uint4*)(qkv + (size_t)(b * S_LEN + gv) * F3 + 2 * EMB + h * DHEAD))[vdg];
        }
        // B: LDS writes visible; do NOT drain vmcnt (prefetch in flight)
        asm volatile("s_waitcnt lgkmcnt(0)" ::: "memory");
        __builtin_amdgcn_s_barrier();
        asm volatile("" ::: "memory");

        // ---- S^T = K Q^T: sf[nt][r] = S[key=nt*16+quad*4+r][q=lane15] ----
        f32x4 sf[4];
        __builtin_amdgcn_s_setprio(1);
        #pragma unroll
        for (int nt = 0; nt < 4; ++nt) {
            f32x4 z = {0.f, 0.f, 0.f, 0.f};
            bf16x8 k0f = *(const bf16x8*)&Ks[nt * 16 + lane15][quad * 8];
            bf16x8 k1f = *(const bf16x8*)&Ks[nt * 16 + lane15][32 + quad * 8];
            z = MFMA16(k0f, qf0, z);
            z = MFMA16(k1f, qf1, z);
            sf[nt] = z;
        }
        __builtin_amdgcn_s_setprio(0);
        const int s0 = ti * 64;
        #pragma unroll
        for (int nt = 0; nt < 4; ++nt)
            #pragma unroll
            for (int r = 0; r < 4; ++r)
                if (s0 + nt * 16 + quad * 4 + r >= S_LEN) sf[nt][r] = -1e30f;

        // ---- row max for q=lane15: 16 local + fold across quads ----
        float mx = fmaxf(fmaxf(sf[0][0], sf[0][1]), fmaxf(sf[0][2], sf[0][3]));
        #pragma unroll
        for (int nt = 1; nt < 4; ++nt)
            mx = fmaxf(mx, fmaxf(fmaxf(sf[nt][0], sf[nt][1]), fmaxf(sf[nt][2], sf[nt][3])));
        mx = fmaxf(mx, __shfl_xor(mx, 16, 64));
        mx = fmaxf(mx, __shfl_xor(mx, 32, 64));

        // ---- T13 defer-max: only rescale when some row grew by > THR ----
        if (!__all(mx - m_i <= 8.0f)) {
            const float mnew  = fmaxf(m_i, mx);
            const float alpha = __expf(m_i - mnew);
            m_i = mnew;
            l_i *= alpha;
            float af[4];
            #pragma unroll
            for (int r = 0; r < 4; ++r)
                af[r] = __shfl(alpha, quad * 4 + r, 64);
            #pragma unroll
            for (int ci = 0; ci < 4; ++ci)
                #pragma unroll
                for (int r = 0; r < 4; ++r)
                    o[ci][r] *= af[r];
        }

        // ---- P = exp(S - m_i), row sum (shared by both paths) ----
        float sum = 0.f;
        #pragma unroll
        for (int nt = 0; nt < 4; ++nt) {
            #pragma unroll
            for (int r = 0; r < 4; ++r) {
                sf[nt][r] = __expf(sf[nt][r] - m_i);
                sum += sf[nt][r];
            }
        }
        sum += __shfl_xor(sum, 16, 64);
        sum += __shfl_xor(sum, 32, 64);
        l_i += sum;

        // ---- P: S^T lane layout -> LDS [q][key] (wave-private rows) ----
        #pragma unroll
        for (int nt = 0; nt < 4; ++nt)
            #pragma unroll
            for (int r = 0; r < 4; ++r)
                Qs[w * 16 + lane15][nt * 16 + quad * 4 + r] = __float2bfloat16(sf[nt][r]);
        asm volatile("s_waitcnt lgkmcnt(0)" ::: "memory");

        // ---- O += P V ----
        __builtin_amdgcn_s_setprio(1);
        #pragma unroll
        for (int s32 = 0; s32 < 2; ++s32) {
            bf16x8 pa = *(const bf16x8*)&Qs[w * 16 + lane15][s32 * 32 + quad * 8];
            #pragma unroll
            for (int ci = 0; ci < 4; ++ci) {
                bf16x8 vb = *(const bf16x8*)&Vt[ci * 16 + lane15][s32 * 32 + quad * 8];
                o[ci] = MFMA16(pa, vb, o[ci]);
            }
        }
        __builtin_amdgcn_s_setprio(0);
    }

    // ---- epilogue: O / l -> attn_out; l for row q=quad*4+r from lane quad*4+r ----
    #pragma unroll
    for (int r = 0; r < 4; ++r) {
        const float lr = __shfl(l_i, quad * 4 + r, 64);
        const int q = q0 + w * 16 + quad * 4 + r;
        if (q < S_LEN) {
            const float rl = 1.0f / lr;
            #pragma unroll
            for (int ci = 0; ci < 4; ++ci) {
                attn_out[(size_t)(b * S_LEN + q) * ldo + h * DHEAD + ci * 16 + lane15] =
                    __float2bfloat16(o[ci][r] * rl);
            }
        }
    }
}

// ---------------------------------------------------------------------------
extern "C" void kernel_launch(void* const* d_in, const int* in_sizes, int n_in,
                              void* d_out, int out_size, void* d_ws, size_t ws_size,
                              hipStream_t stream) {
    const float* x      = (const float*)d_in[0];
    const float* w_qkv  = (const float*)d_in[1];
    const float* w_proj = (const float*)d_in[2];
    for (int i = 0; i < n_in; ++i) {
        if      (in_sizes[i] == 32 * S_LEN * EMB) x      = (const float*)d_in[i];
        else if (in_sizes[i] == F3 * EMB)         w_qkv  = (const float*)d_in[i];
        else if (in_sizes[i] == EMB * EMB)        w_proj = (const float*)d_in[i];
    }
    float* out = (float*)d_out;     // fp32 output (r6-verified)

    const int Mrows = 32 * S_LEN;           // 18464
    const int NX    = Mrows * EMB;          // 14,180,352 (mult of 8)
    const int NWQ   = F3 * EMB;             // 1,769,472  (mult of 8)

    __hip_bfloat16* qkv = (__hip_bfloat16*)d_ws;        // [M][2304] bf16, 81.1 MiB
    // d_out as scratch until K4 overwrites it: xb (28.4 MB) + wb (3.4 MB) < 56.7 MB
    __hip_bfloat16* xb  = (__hip_bfloat16*)d_out;
    __hip_bfloat16* wb  = xb + (size_t)NX;

    // C: both fp32 -> bf16 converts in ONE dispatch
    const int xblocks = NX / 8 / 256;       // 6924 (exact)
    const int wblocks = NWQ / 8 / 256;      // 864  (exact)
    cvt_pair<<<xblocks + wblocks, 256, 0, stream>>>(x, xb, NX / 8, w_qkv, wb, NWQ / 8, xblocks);
    // K1: qkv = xb @ wb^T  (pure-bf16 DMA staging, bf16 C)
    gemm_a_dma<false, false, false><<<dim3(F3 / 128, (Mrows + 127) / 128), 256, 0, stream>>>(
        xb, EMB, wb, EMB, qkv, Mrows, F3, EMB);
    // K3: attention with fused RoPE (512 thr, 128-row Q tiles); O -> q-region
    attn_kernel<<<dim3((S_LEN + 127) / 128, NHEAD, 32), 512, 0, stream>>>(qkv, qkv, F3);
    // K4: out = O @ bf16(w_proj)^T  (A DMA bf16 stride F3; B f32 convert; C f32)
    gemm_a_dma<false, true, true><<<dim3(EMB / 128, (Mrows + 127) / 128), 256, 0, stream>>>(
        qkv, F3, w_proj, EMB, out, Mrows, EMB, EMB);
}